// Round 1
// 203.957 us; speedup vs baseline: 1.0648x; 1.0648x over previous
//
#include <hip/hip_runtime.h>
#include <cstdint>
#include <cstddef>

typedef unsigned short u16;
typedef short short8 __attribute__((ext_vector_type(8)));
typedef float floatx4 __attribute__((ext_vector_type(4)));

#define DEVINL __device__ __forceinline__

static constexpr int BSZ = 8, SEQL = 4096, H = 512, P = 256;
static constexpr int M = BSZ * SEQL;       // 32768 rows
static constexpr int KD = 512;             // K for both GEMMs
static constexpr int ND = 512;             // N for both GEMMs
static constexpr int CHUNK = 64;
static constexpr int NCH = SEQL / CHUNK;   // 64 chunks

DEVINL u16 f2bf(float f) {
  union { float f; unsigned u; } v; v.f = f;
  unsigned r = (v.u + 0x7fffu + ((v.u >> 16) & 1u)) >> 16;
  return (u16)r;
}
DEVINL float bf2f(u16 h) {
  union { unsigned u; float f; } v; v.u = ((unsigned)h) << 16; return v.f;
}

// async global->LDS, 16B per lane. LDS dest must be wave-uniform base + lane*16.
DEVINL void gload_lds16(const u16* g, u16* l) {
  __builtin_amdgcn_global_load_lds(
      (const __attribute__((address_space(1))) unsigned*)g,
      (__attribute__((address_space(3))) unsigned*)l, 16, 0, 0);
}

// ---------- setup: lam[p] = exp(Lambda*step), f[p] = (lam-1)/Lambda ----------
__global__ void setup_kernel(const float* __restrict__ Lre, const float* __restrict__ Lim,
                             const float* __restrict__ logstep,
                             float2* __restrict__ lam, float2* __restrict__ ffac) {
  int p = threadIdx.x;
  if (p >= P) return;
  float lr = Lre[p], li = Lim[p];
  float st = expf(logstep[p]);
  float mag = expf(lr * st);
  float ang = li * st;
  float cr = mag * cosf(ang);
  float ci = mag * sinf(ang);
  lam[p] = make_float2(cr, ci);
  float a = cr - 1.0f, b = ci;
  float den = lr * lr + li * li;
  float fr = (a * lr + b * li) / den;
  float fi = (b * lr - a * li) / den;
  ffac[p] = make_float2(fr, fi);
}

// ---------- Bt1[n=2p+ri][h] = component of f[p]*B_tilde[p][h], bf16 ----------
__global__ void bt1_kernel(const float2* __restrict__ Bin,
                           const float2* __restrict__ ffac,
                           u16* __restrict__ bt1) {
  int idx = blockIdx.x * 256 + threadIdx.x;   // over P*H
  int p = idx / H, h = idx % H;
  float2 bv = Bin[(size_t)p * H + h];
  float2 f = ffac[p];
  float br = f.x * bv.x - f.y * bv.y;
  float bi = f.x * bv.y + f.y * bv.x;
  bt1[(size_t)(2 * p) * H + h]     = f2bf(br);
  bt1[(size_t)(2 * p + 1) * H + h] = f2bf(bi);
}

// ---------- Bt2[h][2p+ri] = +-2 * C[h][p][ri] ----------
__global__ void bt2_kernel(const float* __restrict__ Cin, u16* __restrict__ bt2) {
  int idx = blockIdx.x * 256 + threadIdx.x;   // over H*P*2
  float c = Cin[idx];
  float v = (idx & 1) ? -2.0f * c : 2.0f * c;
  bt2[idx] = f2bf(v);
}

// ---------- u (f32) -> u_bf (bf16), 4 per thread ----------
__global__ void ucvt_kernel(const float4* __restrict__ uin, ushort4* __restrict__ ubf) {
  int idx = blockIdx.x * 256 + threadIdx.x;   // over M*H/4
  float4 f = uin[idx];
  ushort4 o;
  o.x = f2bf(f.x); o.y = f2bf(f.y); o.z = f2bf(f.z); o.w = f2bf(f.w);
  ubf[idx] = o;
}

// ---------- MFMA GEMM: C[M][N] = A[M][K]*Bt[N][K]^T ----------
// Double-buffered LDS, T3-min pipeline: stage(nxt) overlaps ds_read+MFMA(cur);
// single raw s_barrier per K-step, explicit lgkmcnt(0)/vmcnt(0) (no compiler drain).
// MODE 0: store bf16 (Bu).  MODE 1: ys = acc + D[n]*u_bf[m][n], gelu, store f32.
template <int MODE>
__global__ __launch_bounds__(256, 4) void gemm_bt(const u16* __restrict__ A,
                                                  const u16* __restrict__ Bt,
                                                  u16* __restrict__ outBf,
                                                  float* __restrict__ outF,
                                                  const float* __restrict__ Dv,
                                                  const u16* __restrict__ ubf) {
  __shared__ u16 As[2][128 * 32];   // 2 x 8 KB
  __shared__ u16 Bs[2][128 * 32];   // 2 x 8 KB
  const int tid = threadIdx.x;
  const int bm = blockIdx.x, bn = blockIdx.y;
  const int wave = tid >> 6, lane = tid & 63;
  const int quad = lane >> 4, l16 = lane & 15;
  const int wm = (wave & 1) << 6, wn = (wave >> 1) << 6;

  floatx4 acc[4][4] = {};

  const u16* Ab = A + (size_t)bm * 128 * KD;
  const u16* Bb = Bt + (size_t)bn * 128 * KD;
  // staging: thread tid covers (row = j*64 + tid>>2, 16B chunk = tid&3), j=0,1
  const int srow = tid >> 2;
  const int scol = (tid & 3) << 3;   // u16 offset within row

  // prologue: stage k0=0 into buffer 0
  gload_lds16(Ab + (size_t)srow * KD + scol,        &As[0][tid * 8]);
  gload_lds16(Ab + (size_t)(srow + 64) * KD + scol, &As[0][2048 + tid * 8]);
  gload_lds16(Bb + (size_t)srow * KD + scol,        &Bs[0][tid * 8]);
  gload_lds16(Bb + (size_t)(srow + 64) * KD + scol, &Bs[0][2048 + tid * 8]);
  asm volatile("s_waitcnt vmcnt(0)" ::: "memory");
  __builtin_amdgcn_sched_barrier(0);
  __builtin_amdgcn_s_barrier();

  int cur = 0;
  for (int k0 = 0; k0 < KD; k0 += 32) {
    // issue next tile's loads (async; latency hides under ds_read + MFMA)
    if (k0 + 32 < KD) {
      const int nb = cur ^ 1;
      gload_lds16(Ab + (size_t)srow * KD + (k0 + 32) + scol,        &As[nb][tid * 8]);
      gload_lds16(Ab + (size_t)(srow + 64) * KD + (k0 + 32) + scol, &As[nb][2048 + tid * 8]);
      gload_lds16(Bb + (size_t)srow * KD + (k0 + 32) + scol,        &Bs[nb][tid * 8]);
      gload_lds16(Bb + (size_t)(srow + 64) * KD + (k0 + 32) + scol, &Bs[nb][2048 + tid * 8]);
    }

    short8 af[4], bfr[4];
#pragma unroll
    for (int t = 0; t < 4; t++)
      af[t] = *(const short8*)&As[cur][(wm + t * 16 + l16) * 32 + quad * 8];
#pragma unroll
    for (int t = 0; t < 4; t++)
      bfr[t] = *(const short8*)&Bs[cur][(wn + t * 16 + l16) * 32 + quad * 8];

    // all reads of buf[cur] drained before we can cross the barrier below
    asm volatile("s_waitcnt lgkmcnt(0)" ::: "memory");
    __builtin_amdgcn_sched_barrier(0);

    __builtin_amdgcn_s_setprio(1);
#pragma unroll
    for (int tm = 0; tm < 4; tm++)
#pragma unroll
      for (int tn = 0; tn < 4; tn++)
        acc[tm][tn] = __builtin_amdgcn_mfma_f32_16x16x32_bf16(af[tm], bfr[tn], acc[tm][tn], 0, 0, 0);
    __builtin_amdgcn_s_setprio(0);

    // next tile's staging complete; reads of cur complete (lgkm above) -> one barrier
    asm volatile("s_waitcnt vmcnt(0)" ::: "memory");
    __builtin_amdgcn_sched_barrier(0);
    __builtin_amdgcn_s_barrier();
    cur ^= 1;
  }

  // epilogue: C/D layout col = lane&15, row = quad*4 + reg  [m89-verified]
  const int row_base = bm * 128 + wm + quad * 4;
  const int col_base = bn * 128 + wn + l16;
  float dv[4];
  if (MODE == 1) {
#pragma unroll
    for (int tn = 0; tn < 4; tn++) dv[tn] = Dv[col_base + tn * 16];
  }
#pragma unroll
  for (int tm = 0; tm < 4; tm++) {
#pragma unroll
    for (int tn = 0; tn < 4; tn++) {
      int n = col_base + tn * 16;
#pragma unroll
      for (int r = 0; r < 4; r++) {
        int m = row_base + tm * 16 + r;
        float v = acc[tm][tn][r];
        if (MODE == 0) {
          outBf[(size_t)m * ND + n] = f2bf(v);
        } else {
          float uv = bf2f(ubf[(size_t)m * ND + n]);
          float ys = v + dv[tn] * uv;
          // gelu(ys) = ys * sigmoid(1.59577*(ys + 0.044715*ys^3)); exp via HW exp2
          float zz = ys + 0.044715f * (ys * ys * ys);
          float e = __builtin_amdgcn_exp2f(-2.3022082f * zz);
          outF[(size_t)m * ND + n] = ys * __builtin_amdgcn_rcpf(1.0f + e);
        }
      }
    }
  }
}

// ---------- scan pass 1: per-chunk carries ----------
__global__ __launch_bounds__(256) void scan_carry(const u16* __restrict__ Bu,
                                                  const float2* __restrict__ lam,
                                                  float2* __restrict__ carry) {
  int p = threadIdx.x;
  int c = blockIdx.x;
  int b = blockIdx.y;
  float2 lm = lam[p];
  float xr = 0.f, xi = 0.f;
  const u16* base = Bu + ((size_t)b * SEQL + (size_t)c * CHUNK) * 512 + 2 * p;
  for (int l = 0; l < CHUNK; l++) {
    unsigned w = *(const unsigned*)(base + (size_t)l * 512);
    float br = bf2f((u16)(w & 0xffffu));
    float bi = bf2f((u16)(w >> 16));
    float nr = lm.x * xr - lm.y * xi + br;
    float ni = lm.x * xi + lm.y * xr + bi;
    xr = nr; xi = ni;
  }
  carry[((size_t)b * NCH + c) * P + p] = make_float2(xr, xi);
}

// ---------- scan pass 2: sequential prefix over chunks ----------
__global__ __launch_bounds__(256) void scan_prefix(const float2* __restrict__ carry,
                                                   const float2* __restrict__ lam,
                                                   float2* __restrict__ prefix) {
  int p = threadIdx.x;
  int b = blockIdx.x;
  float2 lm = lam[p];
  float ar = lm.x, ai = lm.y;
  for (int i = 0; i < 6; i++) { float nr = ar * ar - ai * ai, ni = 2.f * ar * ai; ar = nr; ai = ni; }
  float pr = 0.f, pi = 0.f;
  for (int c = 0; c < NCH; c++) {
    prefix[((size_t)b * NCH + c) * P + p] = make_float2(pr, pi);
    float2 ca = carry[((size_t)b * NCH + c) * P + p];
    float nr = ar * pr - ai * pi + ca.x;
    float ni = ar * pi + ai * pr + ca.y;
    pr = nr; pi = ni;
  }
}

// ---------- scan pass 3: apply prefix, write xs (bf16, in-place over Bu) ----------
__global__ __launch_bounds__(256) void scan_apply(u16* __restrict__ Bu,
                                                  const float2* __restrict__ lam,
                                                  const float2* __restrict__ prefix) {
  int p = threadIdx.x;
  int c = blockIdx.x;
  int b = blockIdx.y;
  float2 lm = lam[p];
  float2 pf = prefix[((size_t)b * NCH + c) * P + p];
  float xr = pf.x, xi = pf.y;
  u16* base = Bu + ((size_t)b * SEQL + (size_t)c * CHUNK) * 512 + 2 * p;
  for (int l = 0; l < CHUNK; l++) {
    unsigned* addr = (unsigned*)(base + (size_t)l * 512);
    unsigned w = *addr;
    float br = bf2f((u16)(w & 0xffffu));
    float bi = bf2f((u16)(w >> 16));
    float nr = lm.x * xr - lm.y * xi + br;
    float ni = lm.x * xi + lm.y * xr + bi;
    xr = nr; xi = ni;
    *addr = (unsigned)f2bf(nr) | ((unsigned)f2bf(ni) << 16);
  }
}

extern "C" void kernel_launch(void* const* d_in, const int* in_sizes, int n_in,
                              void* d_out, int out_size, void* d_ws, size_t ws_size,
                              hipStream_t stream) {
  const float* u      = (const float*)d_in[0];   // (8,4096,512)
  const float* Lre    = (const float*)d_in[1];   // (256,)
  const float* Lim    = (const float*)d_in[2];   // (256,)
  const float* Bin    = (const float*)d_in[3];   // (256,512,2)
  const float* Cin    = (const float*)d_in[4];   // (512,256,2)
  const float* Dv     = (const float*)d_in[5];   // (512,)
  const float* lstep  = (const float*)d_in[6];   // (256,1)
  float* out          = (float*)d_out;           // (8,4096,512) f32

  char* ws = (char*)d_ws;
  float2* lam    = (float2*)(ws + 0);                 //   2 KB
  float2* ffac   = (float2*)(ws + 2048);              //   2 KB
  u16*    bt1    = (u16*)   (ws + 4096);              // 512 KB
  u16*    bt2    = (u16*)   (ws + 528384);            // 512 KB
  u16*    ubf    = (u16*)   (ws + 1052672);           //  32 MB
  u16*    Bu     = (u16*)   (ws + 34607104);          //  32 MB (becomes xs)
  float2* carry  = (float2*)(ws + 68161536);          //   1 MB
  float2* prefix = (float2*)(ws + 69210112);          //   1 MB

  setup_kernel<<<1, 256, 0, stream>>>(Lre, Lim, lstep, lam, ffac);
  bt1_kernel<<<(P * H) / 256, 256, 0, stream>>>((const float2*)Bin, ffac, bt1);
  bt2_kernel<<<(H * P * 2) / 256, 256, 0, stream>>>(Cin, bt2);
  ucvt_kernel<<<(M * H / 4) / 256, 256, 0, stream>>>((const float4*)u, (ushort4*)ubf);

  gemm_bt<0><<<dim3(M / 128, ND / 128), 256, 0, stream>>>(ubf, bt1, Bu, nullptr, nullptr, nullptr);

  scan_carry <<<dim3(NCH, BSZ), 256, 0, stream>>>(Bu, lam, carry);
  scan_prefix<<<BSZ, 256, 0, stream>>>(carry, lam, prefix);
  scan_apply <<<dim3(NCH, BSZ), 256, 0, stream>>>(Bu, lam, prefix);

  gemm_bt<1><<<dim3(M / 128, ND / 128), 256, 0, stream>>>(Bu, bt2, nullptr, out, Dv, ubf);
}